// Round 7
// baseline (726.483 us; speedup 1.0000x reference)
//
#include <hip/hip_runtime.h>
#include <hip/hip_bf16.h>

// out = x @ W^T + b + 2 * ((x@V) * codes) @ U^T
// M = 16384, N = 4096, K = 4096, rank = 8
//
// Round 7: R6 schedule (470us, 53.5% MfmaUtil) with the MFMA shape switched
// 16x16x32 -> 32x32x16 (measured ceiling 2075 -> 2495 TF, m06/m119): matrix
// floor 265 -> 220 us at identical LDS layout/staging/swizzle/barriers.
// Fragment mapping: A row=lane&31, k=(lane>>5)*8+j; C/D col=lane&31,
// row=(reg&3)+8*(reg>>2)+4*(lane>>5) (m74/m101 measured).

typedef __bf16 bf16_t;
typedef __bf16 bf16x8 __attribute__((ext_vector_type(8)));
typedef float f32x16 __attribute__((ext_vector_type(16)));

#define M_TOT 16384
#define N_TOT 4096
#define K_TOT 4096
#define NT 64  // K-tiles of 64

#define GLOAD_LDS16(gp, lp)                                                    \
  __builtin_amdgcn_global_load_lds(                                            \
      (const __attribute__((address_space(1))) void*)(gp),                     \
      (__attribute__((address_space(3))) void*)(lp), 16, 0, 0)

// ---------------------------------------------------------------- W -> bf16
__global__ void __launch_bounds__(256) conv_w_kernel(const float* __restrict__ W,
                                                     bf16_t* __restrict__ wbf) {
  size_t i = ((size_t)blockIdx.x * 256 + threadIdx.x) * 8;
  const float4* p = (const float4*)(W + i);
  float4 a = p[0], b = p[1];
  bf16x8 v;
  v[0] = (bf16_t)a.x; v[1] = (bf16_t)a.y; v[2] = (bf16_t)a.z; v[3] = (bf16_t)a.w;
  v[4] = (bf16_t)b.x; v[5] = (bf16_t)b.y; v[6] = (bf16_t)b.z; v[7] = (bf16_t)b.w;
  *(bf16x8*)(wbf + i) = v;
}

// ------------------------------------- x -> bf16  +  g = 2*(x@V)*codes
__global__ void __launch_bounds__(256) prep_x_kernel(
    const float* __restrict__ x, const float* __restrict__ codes,
    const float* __restrict__ V, bf16_t* __restrict__ xbf,
    float* __restrict__ g) {
  const int tid = threadIdx.x;
  const int lane = tid & 63;
  const int wv = tid >> 6;
  const int m0 = blockIdx.x * 4;
  const int c0 = tid * 16;

  float xv[4][8];
#pragma unroll
  for (int rr = 0; rr < 4; ++rr)
#pragma unroll
    for (int r = 0; r < 8; ++r) xv[rr][r] = 0.f;

#pragma unroll
  for (int h = 0; h < 2; ++h) {
    const int cb = c0 + h * 8;
    float xr[4][8];
#pragma unroll
    for (int rr = 0; rr < 4; ++rr) {
      const float4* xp = (const float4*)(x + (size_t)(m0 + rr) * K_TOT + cb);
      float4 a0 = xp[0], a1 = xp[1];
      xr[rr][0] = a0.x; xr[rr][1] = a0.y; xr[rr][2] = a0.z; xr[rr][3] = a0.w;
      xr[rr][4] = a1.x; xr[rr][5] = a1.y; xr[rr][6] = a1.z; xr[rr][7] = a1.w;
      bf16x8 bv;
#pragma unroll
      for (int t = 0; t < 8; ++t) bv[t] = (bf16_t)xr[rr][t];
      *(bf16x8*)(xbf + (size_t)(m0 + rr) * K_TOT + cb) = bv;
    }
#pragma unroll
    for (int t = 0; t < 8; ++t) {
      const float4* vp = (const float4*)(V + (size_t)(cb + t) * 8);
      float4 v0 = vp[0], v1 = vp[1];
#pragma unroll
      for (int rr = 0; rr < 4; ++rr) {
        float xi = xr[rr][t];
        xv[rr][0] += xi * v0.x; xv[rr][1] += xi * v0.y;
        xv[rr][2] += xi * v0.z; xv[rr][3] += xi * v0.w;
        xv[rr][4] += xi * v1.x; xv[rr][5] += xi * v1.y;
        xv[rr][6] += xi * v1.z; xv[rr][7] += xi * v1.w;
      }
    }
  }

  __shared__ float red[4][4][8];
#pragma unroll
  for (int rr = 0; rr < 4; ++rr)
#pragma unroll
    for (int r = 0; r < 8; ++r) {
      float v = xv[rr][r];
      for (int s = 32; s > 0; s >>= 1) v += __shfl_down(v, s);
      if (lane == 0) red[wv][rr][r] = v;
    }
  __syncthreads();
  if (tid < 32) {
    int rr = tid >> 3, r = tid & 7;
    float tot = red[0][rr][r] + red[1][rr][r] + red[2][rr][r] + red[3][rr][r];
    int m = m0 + rr;
    g[m * 8 + r] = tot * codes[(size_t)m * 8 + r] * 2.0f;
  }
}

// ------------------------------------------------------------ 256^2 GEMM
#define BAR __builtin_amdgcn_s_barrier()
#define VMC4 asm volatile("s_waitcnt vmcnt(4)" ::: "memory")
#define VMC0 asm volatile("s_waitcnt vmcnt(0)" ::: "memory")

// Stage one half-tile (128 rows x 64 cols) of K-tile KT into lds[DB*2+AB].
#define STAGE(DB, AB, HALF, KT, SRC)                                           \
  {                                                                            \
    _Pragma("unroll") for (int r_ = 0; r_ < 2; ++r_) {                         \
      int rowl_ = (HALF) * 128 + (r_ * 8 + w) * 8 + srow;                      \
      const bf16_t* gp_ = (SRC) + (size_t)rowl_ * K_TOT + (KT) * 64 + sgk;     \
      GLOAD_LDS16(gp_, &lds[(DB) * 2 + (AB)][rowl_ * 64 + sj * 8]);            \
    }                                                                          \
  }

// slot for k-quarter Q (16B units, swizzled): ((Q*2+lq)^xs)*8 elements
#define SLOTQ(Q) ((((Q) * 2 + lq) ^ xs) * 8)

// Read A fragments for mi = MI0..MI0+1, all 4 k-quarters.
#define READ_A2(BUF, MI0, DST)                                                 \
  _Pragma("unroll") for (int mi_ = 0; mi_ < 2; ++mi_)                          \
  _Pragma("unroll") for (int q_ = 0; q_ < 4; ++q_) {                           \
    DST[mi_][q_] = *(const bf16x8*)&lds[(BUF) * 2]                             \
        [arow0 + ((MI0) + mi_) * 2048 + ((((q_) * 2 + lq) ^ xs) * 8)];         \
  }

// Read B fragments for one nj (32 cols), all 4 k-quarters.
#define READ_B2(BUF, NJ, DST)                                                  \
  _Pragma("unroll") for (int q_ = 0; q_ < 4; ++q_) {                           \
    DST[q_] = *(const bf16x8*)&lds[(BUF) * 2 + 1]                              \
        [brow0 + (NJ) * 2048 + ((((q_) * 2 + lq) ^ xs) * 8)];                  \
  }

// 8 MFMA (2 mi x 4 q) of 32x32x16 into acc[MI0..MI0+1][NJ].
#define MFMA_Q32(MI0, NJ, ASRC, BSRC)                                          \
  __builtin_amdgcn_s_setprio(1);                                               \
  _Pragma("unroll") for (int q_ = 0; q_ < 4; ++q_)                             \
  _Pragma("unroll") for (int mi_ = 0; mi_ < 2; ++mi_) {                        \
    acc[(MI0) + mi_][NJ] = __builtin_amdgcn_mfma_f32_32x32x16_bf16(            \
        ASRC[mi_][q_], BSRC[q_], acc[(MI0) + mi_][NJ], 0, 0, 0);               \
  }                                                                            \
  __builtin_amdgcn_s_setprio(0);

// One K-tile = 4 MFMA windows, 5 barriers (R6 skeleton, shape-swapped):
//   pre-W0: stage Ah1(KT+1); vmcnt(4); BAR
//   W0: A mi0-1 (8 rd) + B nj0 (4 rd) reads, MFMA(mi01,nj0), B nj1 prefetch
//   W1: stage Bh0(KT+1) + MFMA(mi01,nj1) + A mi2-3 prefetch (aG)
//   W2: stage Bh1(KT+1) + MFMA(mi23,nj1)
//   W3: stage Ah0(KT+2) + MFMA(mi23,nj0)   [region's reads done >=2 BARs ago]
#define KTILE(BUF, KT, S1, S2, VM)                                             \
  if (S1) STAGE(BUF ^ 1, 0, 1, (KT) + 1, aSrc);                                \
  if ((VM) == 4) { VMC4; } else { VMC0; }                                      \
  BAR;                                                                         \
  READ_A2(BUF, 0, aF);                                                         \
  READ_B2(BUF, 0, b0);                                                         \
  MFMA_Q32(0, 0, aF, b0);                                                      \
  READ_B2(BUF, 1, b1);                                                         \
  BAR;                                                                         \
  if (S1) STAGE(BUF ^ 1, 1, 0, (KT) + 1, bSrc);                                \
  MFMA_Q32(0, 1, aF, b1);                                                      \
  READ_A2(BUF, 2, aG);                                                         \
  BAR;                                                                         \
  if (S1) STAGE(BUF ^ 1, 1, 1, (KT) + 1, bSrc);                                \
  MFMA_Q32(2, 1, aG, b1);                                                      \
  BAR;                                                                         \
  if (S2) STAGE(BUF, 0, 0, (KT) + 2, aSrc);                                    \
  MFMA_Q32(2, 0, aG, b0);                                                      \
  BAR;

__global__ void __launch_bounds__(512) gemm_kernel(
    const bf16_t* __restrict__ A,   // [16384][4096] bf16
    const bf16_t* __restrict__ Bm,  // [4096][4096] bf16
    const float* __restrict__ bias, const float* __restrict__ U,
    const float* __restrict__ g, float* __restrict__ out) {
  const int tid = threadIdx.x;
  const int lane = tid & 63;
  const int w = tid >> 6;  // 0..7
  const int wr = w >> 2;   // 0..1
  const int wc = w & 3;    // 0..3
  const int l32 = lane & 31;  // row/col within 32-frag
  const int lq = lane >> 5;   // k-chunk select (0/1)
  const int xs = lane & 7;    // swizzle key (= row&7 of the frag row)

  // XCD-bijective swizzle: nwg = 1024 (divisible by 8); bn fastest per XCD.
  int bid = blockIdx.x;
  int sw = (bid & 7) * 128 + (bid >> 3);
  const int bm = sw >> 4;  // 0..63
  const int bn = sw & 15;  // 0..15

  __shared__ __attribute__((aligned(128))) bf16_t lds[4][16384];  // 128 KiB

  const bf16_t* aSrc = A + (size_t)bm * 256 * K_TOT;
  const bf16_t* bSrc = Bm + (size_t)bn * 256 * K_TOT;

  // staging per-thread constants (pre-swizzled global k-slot)
  const int srow = lane >> 3;        // row within 8-row chunk (= row & 7)
  const int sj = lane & 7;           // physical LDS slot (linear DMA dest)
  const int sgk = (sj ^ srow) * 8;   // global k-element offset

  // ds_read per-thread bases (element offsets into a 256x64 tile)
  const int arow0 = (wr * 128 + l32) * 64;  // + mi*2048 for mi-th 32-row block
  const int brow0 = (wc * 64 + l32) * 64;   // + nj*2048

  f32x16 acc[4][2] = {};
  bf16x8 aF[2][4], aG[2][4], b0[4], b1[4];

  // Prologue: tile0 all 4 halves + tile1 A-h0. First KTILE's pre-W0 stage
  // brings outstanding to 12; its vmcnt(4) drains exactly tile0's 8.
  STAGE(0, 0, 0, 0, aSrc);
  STAGE(0, 0, 1, 0, aSrc);
  STAGE(0, 1, 0, 0, bSrc);
  STAGE(0, 1, 1, 0, bSrc);
  STAGE(1, 0, 0, 1, aSrc);

#pragma unroll 1
  for (int t = 0; t < NT - 2; t += 2) {
    KTILE(0, t, 1, 1, 4);
    KTILE(1, t + 1, 1, 1, 4);
  }
  KTILE(0, NT - 2, 1, 0, 4);
  KTILE(1, NT - 1, 0, 0, 0);

  // Epilogue: out = acc + bias[n] + dot8(g[m], U[n])
  // C/D 32x32 layout: col = lane&31, row = (reg&3) + 8*(reg>>2) + 4*(lane>>5)
  const int C0 = bn * 256 + wc * 64 + l32;
  float biasv[2];
  float Un[2][8];
#pragma unroll
  for (int nj = 0; nj < 2; ++nj) {
    int n = C0 + nj * 32;
    biasv[nj] = bias[n];
    const float4* up = (const float4*)(U + (size_t)n * 8);
    float4 u0 = up[0], u1 = up[1];
    Un[nj][0] = u0.x; Un[nj][1] = u0.y; Un[nj][2] = u0.z; Un[nj][3] = u0.w;
    Un[nj][4] = u1.x; Un[nj][5] = u1.y; Un[nj][6] = u1.z; Un[nj][7] = u1.w;
  }
#pragma unroll
  for (int mi = 0; mi < 4; ++mi) {
#pragma unroll
    for (int h = 0; h < 4; ++h) {
      const int r0 = bm * 256 + wr * 128 + mi * 32 + 4 * lq + 8 * h;
      float gv[4][8];
#pragma unroll
      for (int rr = 0; rr < 4; ++rr) {
        const float4* gp = (const float4*)(g + (size_t)(r0 + rr) * 8);
        float4 g0 = gp[0], g1 = gp[1];
        gv[rr][0] = g0.x; gv[rr][1] = g0.y; gv[rr][2] = g0.z; gv[rr][3] = g0.w;
        gv[rr][4] = g1.x; gv[rr][5] = g1.y; gv[rr][6] = g1.z; gv[rr][7] = g1.w;
      }
#pragma unroll
      for (int nj = 0; nj < 2; ++nj) {
#pragma unroll
        for (int rr = 0; rr < 4; ++rr) {
          const int reg = h * 4 + rr;
          float lora = gv[rr][0] * Un[nj][0] + gv[rr][1] * Un[nj][1] +
                       gv[rr][2] * Un[nj][2] + gv[rr][3] * Un[nj][3] +
                       gv[rr][4] * Un[nj][4] + gv[rr][5] * Un[nj][5] +
                       gv[rr][6] * Un[nj][6] + gv[rr][7] * Un[nj][7];
          out[(size_t)(r0 + rr) * N_TOT + C0 + nj * 32] =
              acc[mi][nj][reg] + biasv[nj] + lora;
        }
      }
    }
  }
}

// ------------------------------------------------- fallback (tiny ws): naive
__global__ void __launch_bounds__(256) naive_kernel(
    const float* __restrict__ x, const float* __restrict__ codes,
    const float* __restrict__ W, const float* __restrict__ bias,
    const float* __restrict__ U, const float* __restrict__ V,
    float* __restrict__ out) {
  int m = blockIdx.x >> 4;
  int n = ((blockIdx.x & 15) << 8) + threadIdx.x;
  const float* xr = x + (size_t)m * K_TOT;
  const float* wrow = W + (size_t)n * K_TOT;
  float acc = 0.f;
  float xv[8] = {0, 0, 0, 0, 0, 0, 0, 0};
  for (int k = 0; k < K_TOT; k += 4) {
    float4 xa = *(const float4*)(xr + k);
    float4 wa = *(const float4*)(wrow + k);
    acc += xa.x * wa.x + xa.y * wa.y + xa.z * wa.z + xa.w * wa.w;
    const float* xs = (const float*)&xa;
#pragma unroll
    for (int t = 0; t < 4; ++t) {
      const float* vrow = V + (size_t)(k + t) * 8;
      float xi = xs[t];
#pragma unroll
      for (int r = 0; r < 8; ++r) xv[r] += xi * vrow[r];
    }
  }
  float lora = 0.f;
#pragma unroll
  for (int r = 0; r < 8; ++r)
    lora += xv[r] * codes[(size_t)m * 8 + r] * U[(size_t)n * 8 + r];
  out[(size_t)m * N_TOT + n] = acc + bias[n] + 2.0f * lora;
}

extern "C" void kernel_launch(void* const* d_in, const int* in_sizes, int n_in,
                              void* d_out, int out_size, void* d_ws,
                              size_t ws_size, hipStream_t stream) {
  const float* x = (const float*)d_in[0];
  const float* codes = (const float*)d_in[1];
  const float* W = (const float*)d_in[2];
  const float* b = (const float*)d_in[3];
  const float* U = (const float*)d_in[4];
  const float* V = (const float*)d_in[5];
  float* out = (float*)d_out;

  const size_t xbf_bytes = (size_t)M_TOT * K_TOT * 2;  // 128 MiB
  const size_t wbf_bytes = (size_t)N_TOT * K_TOT * 2;  // 32 MiB
  const size_t g_bytes = (size_t)M_TOT * 8 * 4;        // 512 KiB

  if (ws_size >= xbf_bytes + wbf_bytes + g_bytes) {
    bf16_t* xbf = (bf16_t*)d_ws;
    bf16_t* wbf = (bf16_t*)((char*)d_ws + xbf_bytes);
    float* g = (float*)((char*)d_ws + xbf_bytes + wbf_bytes);
    hipLaunchKernelGGL(conv_w_kernel, dim3(8192), dim3(256), 0, stream, W, wbf);
    hipLaunchKernelGGL(prep_x_kernel, dim3(4096), dim3(256), 0, stream, x,
                       codes, V, xbf, g);
    hipLaunchKernelGGL(gemm_kernel, dim3(1024), dim3(512), 0, stream, xbf, wbf,
                       b, U, g, out);
  } else {
    hipLaunchKernelGGL(naive_kernel, dim3((M_TOT) * (N_TOT / 256)), dim3(256),
                       0, stream, x, codes, W, b, U, V, out);
  }
}

// Round 8
// 607.033 us; speedup vs baseline: 1.1968x; 1.1968x over previous
//
#include <hip/hip_runtime.h>
#include <hip/hip_bf16.h>

// out = x @ W^T + b + 2 * ((x@V) * codes) @ U^T
// M = 16384, N = 4096, K = 4096, rank = 8
//
// Round 8: GEMM reverted to R6 verbatim (470us, 53.5% MfmaUtil — best known;
// R3/R4/R7 restructures all regressed). Prep path fused into ONE kernel:
// blocks [0,4096) do x->bf16 + g = 2*(x@V)*codes (the long pole, scheduled
// first), blocks [4096,12288) do W->bf16. Saves a launch and overlaps the
// two memory-bound phases.

typedef __bf16 bf16_t;
typedef __bf16 bf16x8 __attribute__((ext_vector_type(8)));
typedef float f32x4 __attribute__((ext_vector_type(4)));

#define M_TOT 16384
#define N_TOT 4096
#define K_TOT 4096
#define NT 64  // K-tiles of 64

#define GLOAD_LDS16(gp, lp)                                                    \
  __builtin_amdgcn_global_load_lds(                                            \
      (const __attribute__((address_space(1))) void*)(gp),                     \
      (__attribute__((address_space(3))) void*)(lp), 16, 0, 0)

// ------------------------- fused prep: x->bf16 + g, and W->bf16 ------------
__global__ void __launch_bounds__(256) prep_fused_kernel(
    const float* __restrict__ x, const float* __restrict__ codes,
    const float* __restrict__ V, const float* __restrict__ W,
    bf16_t* __restrict__ xbf, bf16_t* __restrict__ wbf,
    float* __restrict__ g) {
  const int tid = threadIdx.x;
  if (blockIdx.x >= 4096) {
    // ---- W -> bf16 (blocks 4096..12287 cover 4096x4096 elems, 8/thread)
    size_t i = ((size_t)(blockIdx.x - 4096) * 256 + tid) * 8;
    const float4* p = (const float4*)(W + i);
    float4 a = p[0], b = p[1];
    bf16x8 v;
    v[0] = (bf16_t)a.x; v[1] = (bf16_t)a.y; v[2] = (bf16_t)a.z; v[3] = (bf16_t)a.w;
    v[4] = (bf16_t)b.x; v[5] = (bf16_t)b.y; v[6] = (bf16_t)b.z; v[7] = (bf16_t)b.w;
    *(bf16x8*)(wbf + i) = v;
    return;
  }
  // ---- x -> bf16 + g = 2*(x@V)*codes (blocks 0..4095, 4 rows each)
  const int lane = tid & 63;
  const int wv = tid >> 6;
  const int m0 = blockIdx.x * 4;
  const int c0 = tid * 16;

  float xv[4][8];
#pragma unroll
  for (int rr = 0; rr < 4; ++rr)
#pragma unroll
    for (int r = 0; r < 8; ++r) xv[rr][r] = 0.f;

#pragma unroll
  for (int h = 0; h < 2; ++h) {
    const int cb = c0 + h * 8;
    float xr[4][8];
#pragma unroll
    for (int rr = 0; rr < 4; ++rr) {
      const float4* xp = (const float4*)(x + (size_t)(m0 + rr) * K_TOT + cb);
      float4 a0 = xp[0], a1 = xp[1];
      xr[rr][0] = a0.x; xr[rr][1] = a0.y; xr[rr][2] = a0.z; xr[rr][3] = a0.w;
      xr[rr][4] = a1.x; xr[rr][5] = a1.y; xr[rr][6] = a1.z; xr[rr][7] = a1.w;
      bf16x8 bv;
#pragma unroll
      for (int t = 0; t < 8; ++t) bv[t] = (bf16_t)xr[rr][t];
      *(bf16x8*)(xbf + (size_t)(m0 + rr) * K_TOT + cb) = bv;
    }
#pragma unroll
    for (int t = 0; t < 8; ++t) {
      const float4* vp = (const float4*)(V + (size_t)(cb + t) * 8);
      float4 v0 = vp[0], v1 = vp[1];
#pragma unroll
      for (int rr = 0; rr < 4; ++rr) {
        float xi = xr[rr][t];
        xv[rr][0] += xi * v0.x; xv[rr][1] += xi * v0.y;
        xv[rr][2] += xi * v0.z; xv[rr][3] += xi * v0.w;
        xv[rr][4] += xi * v1.x; xv[rr][5] += xi * v1.y;
        xv[rr][6] += xi * v1.z; xv[rr][7] += xi * v1.w;
      }
    }
  }

  __shared__ float red[4][4][8];
#pragma unroll
  for (int rr = 0; rr < 4; ++rr)
#pragma unroll
    for (int r = 0; r < 8; ++r) {
      float v = xv[rr][r];
      for (int s = 32; s > 0; s >>= 1) v += __shfl_down(v, s);
      if (lane == 0) red[wv][rr][r] = v;
    }
  __syncthreads();
  if (tid < 32) {
    int rr = tid >> 3, r = tid & 7;
    float tot = red[0][rr][r] + red[1][rr][r] + red[2][rr][r] + red[3][rr][r];
    int m = m0 + rr;
    g[m * 8 + r] = tot * codes[(size_t)m * 8 + r] * 2.0f;
  }
}

// ------------------------------------------------------------ 256^2 GEMM
#define BAR __builtin_amdgcn_s_barrier()
#define VMC4 asm volatile("s_waitcnt vmcnt(4)" ::: "memory")
#define VMC0 asm volatile("s_waitcnt vmcnt(0)" ::: "memory")

// Stage one half-tile (128 rows x 64 cols) of K-tile KT into lds[DB*2+AB].
#define STAGE(DB, AB, HALF, KT, SRC)                                           \
  {                                                                            \
    _Pragma("unroll") for (int r_ = 0; r_ < 2; ++r_) {                         \
      int rowl_ = (HALF) * 128 + (r_ * 8 + w) * 8 + srow;                      \
      const bf16_t* gp_ = (SRC) + (size_t)rowl_ * K_TOT + (KT) * 64 + sgk;     \
      GLOAD_LDS16(gp_, &lds[(DB) * 2 + (AB)][rowl_ * 64 + sj * 8]);            \
    }                                                                          \
  }

#define READ_A(BUF, MI0, DST)                                                  \
  _Pragma("unroll") for (int mi_ = 0; mi_ < 4; ++mi_) {                        \
    DST[mi_][0] = *(const bf16x8*)&lds[(BUF) * 2][arow0 + ((MI0) + mi_) * 1024 + aslot0]; \
    DST[mi_][1] = *(const bf16x8*)&lds[(BUF) * 2][arow0 + ((MI0) + mi_) * 1024 + aslot1]; \
  }

#define READ_B(BUF, NJ0, DST)                                                  \
  _Pragma("unroll") for (int nj_ = 0; nj_ < 2; ++nj_) {                        \
    DST[nj_][0] = *(const bf16x8*)&lds[(BUF) * 2 + 1][brow0 + ((NJ0) + nj_) * 1024 + aslot0]; \
    DST[nj_][1] = *(const bf16x8*)&lds[(BUF) * 2 + 1][brow0 + ((NJ0) + nj_) * 1024 + aslot1]; \
  }

#define MFMA_Q(MI0, NJ0, ASRC, BSRC)                                           \
  __builtin_amdgcn_s_setprio(1);                                               \
  _Pragma("unroll") for (int mi_ = 0; mi_ < 4; ++mi_)                          \
  _Pragma("unroll") for (int nj_ = 0; nj_ < 2; ++nj_) {                        \
    acc[(MI0) + mi_][(NJ0) + nj_] = __builtin_amdgcn_mfma_f32_16x16x32_bf16(   \
        ASRC[mi_][0], BSRC[nj_][0], acc[(MI0) + mi_][(NJ0) + nj_], 0, 0, 0);   \
    acc[(MI0) + mi_][(NJ0) + nj_] = __builtin_amdgcn_mfma_f32_16x16x32_bf16(   \
        ASRC[mi_][1], BSRC[nj_][1], acc[(MI0) + mi_][(NJ0) + nj_], 0, 0, 0);   \
  }                                                                            \
  __builtin_amdgcn_s_setprio(0);

// One K-tile = 4 MFMA windows, 5 barriers (R6 structure, proven best):
//   pre-W0: stage Ah1(KT+1); vmcnt(4); BAR
//   W0: A0-3,B01 reads + MFMA(0,0) + B23 prefetch
//   W1: stage Bh0(KT+1) + MFMA(0,2) + A4-7 prefetch (aG)
//   W2: stage Bh1(KT+1) + MFMA(4,2)
//   W3: stage Ah0(KT+2) + MFMA(4,0)
#define KTILE(BUF, KT, S1, S2, VM)                                             \
  if (S1) STAGE(BUF ^ 1, 0, 1, (KT) + 1, aSrc);                                \
  if ((VM) == 4) { VMC4; } else { VMC0; }                                      \
  BAR;                                                                         \
  READ_A(BUF, 0, aF);                                                          \
  READ_B(BUF, 0, b01);                                                         \
  MFMA_Q(0, 0, aF, b01);                                                       \
  READ_B(BUF, 2, b23);                                                         \
  BAR;                                                                         \
  if (S1) STAGE(BUF ^ 1, 1, 0, (KT) + 1, bSrc);                                \
  MFMA_Q(0, 2, aF, b23);                                                       \
  READ_A(BUF, 4, aG);                                                          \
  BAR;                                                                         \
  if (S1) STAGE(BUF ^ 1, 1, 1, (KT) + 1, bSrc);                                \
  MFMA_Q(4, 2, aG, b23);                                                       \
  BAR;                                                                         \
  if (S2) STAGE(BUF, 0, 0, (KT) + 2, aSrc);                                    \
  MFMA_Q(4, 0, aG, b01);                                                       \
  BAR;

__global__ void __launch_bounds__(512) gemm_kernel(
    const bf16_t* __restrict__ A,   // [16384][4096] bf16
    const bf16_t* __restrict__ Bm,  // [4096][4096] bf16
    const float* __restrict__ bias, const float* __restrict__ U,
    const float* __restrict__ g, float* __restrict__ out) {
  const int tid = threadIdx.x;
  const int lane = tid & 63;
  const int w = tid >> 6;  // 0..7
  const int wr = w >> 2;   // 0..1
  const int wc = w & 3;    // 0..3
  const int llo = lane & 15, lhi = lane >> 4;

  // XCD-bijective swizzle: nwg = 1024 (divisible by 8); bn fastest per XCD.
  int bid = blockIdx.x;
  int sw = (bid & 7) * 128 + (bid >> 3);
  const int bm = sw >> 4;  // 0..63
  const int bn = sw & 15;  // 0..15

  __shared__ __attribute__((aligned(128))) bf16_t lds[4][16384];  // 128 KiB

  const bf16_t* aSrc = A + (size_t)bm * 256 * K_TOT;
  const bf16_t* bSrc = Bm + (size_t)bn * 256 * K_TOT;

  // staging per-thread constants (pre-swizzled global k-slot)
  const int srow = lane >> 3;        // row within 8-row chunk (= row & 7)
  const int sj = lane & 7;           // physical LDS slot (linear DMA dest)
  const int sgk = (sj ^ srow) * 8;   // global k-element offset

  // ds_read per-thread bases (element offsets into a 256x64 tile)
  const int xs = llo & 7;
  const int arow0 = (wr * 128 + llo) * 64;
  const int brow0 = (wc * 64 + llo) * 64;
  const int aslot0 = ((0 + lhi) ^ xs) * 8;  // kk=0
  const int aslot1 = ((4 + lhi) ^ xs) * 8;  // kk=1

  f32x4 acc[8][4] = {};
  bf16x8 aF[4][2], aG[4][2], b01[2][2], b23[2][2];

  // Prologue: tile0 all 4 halves + tile1 A-h0. First KTILE's pre-W0 stage
  // brings outstanding to 12; its vmcnt(4) drains exactly tile0's 8.
  STAGE(0, 0, 0, 0, aSrc);
  STAGE(0, 0, 1, 0, aSrc);
  STAGE(0, 1, 0, 0, bSrc);
  STAGE(0, 1, 1, 0, bSrc);
  STAGE(1, 0, 0, 1, aSrc);

#pragma unroll 1
  for (int t = 0; t < NT - 2; t += 2) {
    KTILE(0, t, 1, 1, 4);
    KTILE(1, t + 1, 1, 1, 4);
  }
  KTILE(0, NT - 2, 1, 0, 4);
  KTILE(1, NT - 1, 0, 0, 0);

  // Epilogue: out = acc + bias[n] + dot8(g[m], U[n])
  const int n0 = bn * 256 + wc * 64;
  int nidx[4];
  float biasv[4];
  float Un[4][8];
#pragma unroll
  for (int nj = 0; nj < 4; ++nj) {
    int n = n0 + nj * 16 + llo;
    nidx[nj] = n;
    biasv[nj] = bias[n];
    const float4* up = (const float4*)(U + (size_t)n * 8);
    float4 u0 = up[0], u1 = up[1];
    Un[nj][0] = u0.x; Un[nj][1] = u0.y; Un[nj][2] = u0.z; Un[nj][3] = u0.w;
    Un[nj][4] = u1.x; Un[nj][5] = u1.y; Un[nj][6] = u1.z; Un[nj][7] = u1.w;
  }
#pragma unroll
  for (int mi = 0; mi < 8; ++mi) {
#pragma unroll
    for (int reg = 0; reg < 4; ++reg) {
      int m = bm * 256 + wr * 128 + mi * 16 + lhi * 4 + reg;
      const float4* gp = (const float4*)(g + m * 8);
      float4 g0 = gp[0], g1 = gp[1];
      float* orow = out + (size_t)m * N_TOT;
#pragma unroll
      for (int nj = 0; nj < 4; ++nj) {
        float lora = g0.x * Un[nj][0] + g0.y * Un[nj][1] + g0.z * Un[nj][2] +
                     g0.w * Un[nj][3] + g1.x * Un[nj][4] + g1.y * Un[nj][5] +
                     g1.z * Un[nj][6] + g1.w * Un[nj][7];
        orow[nidx[nj]] = acc[mi][nj][reg] + biasv[nj] + lora;
      }
    }
  }
}

// ------------------------------------------------- fallback (tiny ws): naive
__global__ void __launch_bounds__(256) naive_kernel(
    const float* __restrict__ x, const float* __restrict__ codes,
    const float* __restrict__ W, const float* __restrict__ bias,
    const float* __restrict__ U, const float* __restrict__ V,
    float* __restrict__ out) {
  int m = blockIdx.x >> 4;
  int n = ((blockIdx.x & 15) << 8) + threadIdx.x;
  const float* xr = x + (size_t)m * K_TOT;
  const float* wrow = W + (size_t)n * K_TOT;
  float acc = 0.f;
  float xv[8] = {0, 0, 0, 0, 0, 0, 0, 0};
  for (int k = 0; k < K_TOT; k += 4) {
    float4 xa = *(const float4*)(xr + k);
    float4 wa = *(const float4*)(wrow + k);
    acc += xa.x * wa.x + xa.y * wa.y + xa.z * wa.z + xa.w * wa.w;
    const float* xs = (const float*)&xa;
#pragma unroll
    for (int t = 0; t < 4; ++t) {
      const float* vrow = V + (size_t)(k + t) * 8;
      float xi = xs[t];
#pragma unroll
      for (int r = 0; r < 8; ++r) xv[r] += xi * vrow[r];
    }
  }
  float lora = 0.f;
#pragma unroll
  for (int r = 0; r < 8; ++r)
    lora += xv[r] * codes[(size_t)m * 8 + r] * U[(size_t)n * 8 + r];
  out[(size_t)m * N_TOT + n] = acc + bias[n] + 2.0f * lora;
}

extern "C" void kernel_launch(void* const* d_in, const int* in_sizes, int n_in,
                              void* d_out, int out_size, void* d_ws,
                              size_t ws_size, hipStream_t stream) {
  const float* x = (const float*)d_in[0];
  const float* codes = (const float*)d_in[1];
  const float* W = (const float*)d_in[2];
  const float* b = (const float*)d_in[3];
  const float* U = (const float*)d_in[4];
  const float* V = (const float*)d_in[5];
  float* out = (float*)d_out;

  const size_t xbf_bytes = (size_t)M_TOT * K_TOT * 2;  // 128 MiB
  const size_t wbf_bytes = (size_t)N_TOT * K_TOT * 2;  // 32 MiB
  const size_t g_bytes = (size_t)M_TOT * 8 * 4;        // 512 KiB

  if (ws_size >= xbf_bytes + wbf_bytes + g_bytes) {
    bf16_t* xbf = (bf16_t*)d_ws;
    bf16_t* wbf = (bf16_t*)((char*)d_ws + xbf_bytes);
    float* g = (float*)((char*)d_ws + xbf_bytes + wbf_bytes);
    hipLaunchKernelGGL(prep_fused_kernel, dim3(12288), dim3(256), 0, stream,
                       x, codes, V, W, xbf, wbf, g);
    hipLaunchKernelGGL(gemm_kernel, dim3(1024), dim3(512), 0, stream, xbf, wbf,
                       b, U, g, out);
  } else {
    hipLaunchKernelGGL(naive_kernel, dim3((M_TOT) * (N_TOT / 256)), dim3(256),
                       0, stream, x, codes, W, b, U, V, out);
  }
}